// Round 13
// baseline (426.923 us; speedup 1.0000x reference)
//
#include <hip/hip_runtime.h>
#include <math.h>

#define NS 4096

typedef _Float16 half8 __attribute__((ext_vector_type(8)));
typedef _Float16 half2v __attribute__((ext_vector_type(2)));
typedef float floatx16 __attribute__((ext_vector_type(16)));

// ---------------- LDS layout (f32 word offsets), main kernel ----------------
#define P1T_OFF     0
#define P1T_STRIDE  72
#define P2T_OFF     9360
#define P2T_STRIDE  136
#define XC_OFF      9360
#define XC_STRIDE   648
#define SCR_OFF     1024
#define B1_OFF      18200
#define B2_OFF      18264
#define B3_OFF      18392
#define PR_OFF      18648
#define LDS_MAIN_FLOATS 19288   // 77,152 B -> 2 blocks/CU

// ---------------- weight prep: f32 -> f16 MFMA layouts ----------------
// w1p[64 m][128 k] (k<100 real, else 0); w2p[5][128 m][64 i]; w3p[3][256 m][128 i]
__global__ void prep_weights(const float* __restrict__ w1,
                             const float* __restrict__ w2,
                             const float* __restrict__ w3,
                             _Float16* __restrict__ w1p,
                             _Float16* __restrict__ w2p,
                             _Float16* __restrict__ w3p)
{
    int gid = blockIdx.x * 256 + threadIdx.x;
    if (gid < 8192) {
        int m = gid >> 7, k = gid & 127;
        w1p[gid] = (k < 100) ? (_Float16)w1[m * 100 + k] : (_Float16)0.f;
    } else if (gid < 49152) {
        int r = gid - 8192;
        int dk = r >> 13, rem = r & 8191;
        int m = rem >> 6, i = rem & 63;
        w2p[r] = (_Float16)w2[(m * 64 + i) * 5 + dk];
    } else if (gid < 147456) {
        int r = gid - 49152;
        int dk = r >> 15, rem = r & 32767;
        int m = rem >> 7, i = rem & 127;
        w3p[r] = (_Float16)w3[(m * 128 + i) * 3 + dk];
    }
}

// inclusive add-scan within each 16-lane row via DPP row_shr; lane (l%16)==15 holds row sum
__device__ __forceinline__ float dpp_rowsum16(float v) {
    int x;
    x = __builtin_amdgcn_update_dpp(0, __float_as_int(v), 0x111, 0xF, 0xF, true);
    v += __int_as_float(x);
    x = __builtin_amdgcn_update_dpp(0, __float_as_int(v), 0x112, 0xF, 0xF, true);
    v += __int_as_float(x);
    x = __builtin_amdgcn_update_dpp(0, __float_as_int(v), 0x114, 0xF, 0xF, true);
    v += __int_as_float(x);
    x = __builtin_amdgcn_update_dpp(0, __float_as_int(v), 0x118, 0xF, 0xF, true);
    v += __int_as_float(x);
    return v;
}

// C/D 32x32 layout: col = lane&31, row = (reg&3) + 8*(reg>>2) + 4*(lane>>5)
// A/B layout: m|n = lane&31, k = (lane>>5)*8 + j (+16*kb)

__global__ __launch_bounds__(512, 4)
void cnn_fused(const float* __restrict__ samples, const int* __restrict__ info,
               const _Float16* __restrict__ w1p,
               const _Float16* __restrict__ w2p,
               const _Float16* __restrict__ w3p,
               const float* __restrict__ b1, const float* __restrict__ b2,
               const float* __restrict__ b3,
               const float* __restrict__ fcw, const float* __restrict__ fcb,
               const float* __restrict__ gamma_, const float* __restrict__ beta_,
               const float* __restrict__ bnm, const float* __restrict__ bnv,
               _Float16* __restrict__ zh, float* __restrict__ sqout,
               int* __restrict__ uout)
{
    extern __shared__ float lds[];
    _Float16* p1T = (_Float16*)(lds + P1T_OFF);
    _Float16* p2T = (_Float16*)(lds + P2T_OFF);
    _Float16* xc  = (_Float16*)(lds + XC_OFF);     // aliases p2T (dead after conv1)

    const int n    = blockIdx.x;
    const int t    = threadIdx.x;
    const int lane = t & 63;
    const int wave = t >> 6;
    const int g    = lane >> 5;
    const int col  = lane & 31;

    // ---- stage: xc[c][u] = x[u + c - 49] as f16; wave w fills copy c=w (no div)
    {
        const float* sp = samples + n * 512;
        const int c = wave;
        for (int u = lane; u < XC_STRIDE; u += 64) {
            int src = u + c - 49;
            xc[c * XC_STRIDE + u] = (_Float16)((src >= 0 && src < 512) ? sp[src] : 0.f);
        }
    }
    // ---- biases + fc/bn params to LDS (hidden under conv1)
    if (t < 64)              lds[B1_OFF + t] = b1[t];
    if (t >= 64 && t < 192)  lds[B2_OFF + (t - 64)] = b2[t - 64];
    if (t >= 192 && t < 448) lds[B3_OFF + (t - 192)] = b3[t - 192];
    for (int i = t; i < 640; i += 512) {
        int k = i & 127;
        const float* p = (i < 128) ? fcb : (i < 256) ? gamma_ : (i < 384) ? beta_
                       : (i < 512) ? bnm : bnv;
        lds[PR_OFF + i] = p[k];
    }
    // ---- zero p1T halos: rows {0,1,258,259} (36 f32 each)
    if (t < 144) {
        int rr = t / 36, c4 = t - rr * 36;
        int row = (rr < 2) ? rr : (256 + rr);
        lds[P1T_OFF + row * 36 + c4] = 0.f;
    }
    if (t == 0) uout[n] = (info[2 * n + 1] == 1) ? info[2 * n] : -1;

    // ---- cross-barrier prefetch: conv1 A[0..1] (global, independent of LDS)
    const int mt1 = wave >> 2;
    const _Float16* ap1 = w1p + (mt1 * 32 + col) * 128 + g * 8;
    half8 a1_0 = *(const half8*)(ap1);
    half8 a1_1 = *(const half8*)(ap1 + 16);
    __syncthreads();

    // pooled relu store: vm duplicated in lane pairs; even lanes write f16 transposed
    auto pool_store = [&](floatx16& acc, _Float16* dst) {
        float vm[16];
        #pragma unroll
        for (int r = 0; r < 16; ++r) {
            float v = fmaxf(acc[r], 0.f);
            vm[r] = fmaxf(v, __shfl_xor(v, 1));
        }
        if (!(lane & 1)) {
            #pragma unroll
            for (int rq = 0; rq < 4; ++rq) {
                half2v p0, p1;
                p0[0] = (_Float16)vm[4 * rq];     p0[1] = (_Float16)vm[4 * rq + 1];
                p1[0] = (_Float16)vm[4 * rq + 2]; p1[1] = (_Float16)vm[4 * rq + 3];
                *(half2v*)(dst + 8 * rq)     = p0;
                *(half2v*)(dst + 8 * rq + 2) = p1;
            }
        }
    };

    // ======== conv1: wave -> (mt = wave>>2, 4 nts); K=112; kb-outer 4-chain stream ========
    {
        const int mt   = mt1;
        const int ntb1 = (wave & 3) * 4;
        const _Float16* ap = ap1;
        const _Float16* bps[4];
        #pragma unroll
        for (int s = 0; s < 4; ++s) {
            const int nt = ntb1 + s;
            const int nn = nt * 32 + col;
            const int c  = nn & 7;
            bps[s] = xc + c * XC_STRIDE + (nn - c) + g * 8;
        }
        floatx16 acc[4];
        #pragma unroll
        for (int q4 = 0; q4 < 4; ++q4) {
            float4 bq = *(const float4*)&lds[B1_OFF + mt * 32 + 8 * q4 + 4 * g];
            #pragma unroll
            for (int s = 0; s < 4; ++s) {
                acc[s][4 * q4 + 0] = bq.x; acc[s][4 * q4 + 1] = bq.y;
                acc[s][4 * q4 + 2] = bq.z; acc[s][4 * q4 + 3] = bq.w;
            }
        }
        half8 Aa[3], Bb[2][4];
        Aa[0] = a1_0;
        Aa[1] = a1_1;
        #pragma unroll
        for (int s = 0; s < 4; ++s) Bb[0][s] = *(const half8*)(bps[s]);
        #pragma unroll
        for (int i = 0; i < 7; ++i) {
            if (i < 5)
                Aa[(i + 2) % 3] = *(const half8*)(ap + (i + 2) * 16);
            if (i < 6) {
                #pragma unroll
                for (int s = 0; s < 4; ++s)
                    Bb[(i + 1) & 1][s] = *(const half8*)(bps[s] + (i + 1) * 16);
            }
            #pragma unroll
            for (int s = 0; s < 4; ++s)
                acc[s] = __builtin_amdgcn_mfma_f32_32x32x16_f16(Aa[i % 3], Bb[i & 1][s], acc[s], 0, 0, 0);
        }
        #pragma unroll
        for (int s = 0; s < 4; ++s) {
            const int P = 2 + (ntb1 + s) * 16 + (col >> 1);
            pool_store(acc[s], p1T + P * P1T_STRIDE + mt * 32 + 4 * g);
        }
    }
    // ---- cross-barrier prefetch: conv2 A[0..1] (acc dead here; lives only through barrier)
    const int mt2 = wave & 3;
    const _Float16* ap2 = w2p + (mt2 * 32 + col) * 64 + g * 8;   // + dk*8192 + kb*16
    half8 a2_0 = *(const half8*)(ap2);
    half8 a2_1 = *(const half8*)(ap2 + 16);
    __syncthreads();

    // ======== conv2: wave -> (mt = wave&3, 4 nts); 20 steps (dk=i>>2, kb=i&3) streamed ========
    {
        // zero p2T halo rows {0,129} now that xc (aliased) is dead
        if (t < 136) {
            int row = (t < 68) ? 0 : 129;
            int c4 = (t < 68) ? t : (t - 68);
            lds[P2T_OFF + row * 68 + c4] = 0.f;
        }
        const int mt  = mt2;
        const int ntb = (wave >> 2) * 4;
        const _Float16* ap = ap2;
        const _Float16* bps[4];
        #pragma unroll
        for (int s = 0; s < 4; ++s)
            bps[s] = p1T + ((ntb + s) * 32 + col) * P1T_STRIDE + g * 8;  // + dk*72 + kb*16
        floatx16 acc[4];
        #pragma unroll
        for (int q4 = 0; q4 < 4; ++q4) {
            float4 bq = *(const float4*)&lds[B2_OFF + mt * 32 + 8 * q4 + 4 * g];
            #pragma unroll
            for (int s = 0; s < 4; ++s) {
                acc[s][4 * q4 + 0] = bq.x; acc[s][4 * q4 + 1] = bq.y;
                acc[s][4 * q4 + 2] = bq.z; acc[s][4 * q4 + 3] = bq.w;
            }
        }
        half8 Aa[3], Bb[2][4];
        Aa[0] = a2_0;
        Aa[1] = a2_1;
        #pragma unroll
        for (int s = 0; s < 4; ++s) Bb[0][s] = *(const half8*)(bps[s]);
        #pragma unroll
        for (int i = 0; i < 20; ++i) {
            if (i < 18) {
                const int j = i + 2, dkj = j >> 2, kbj = j & 3;
                Aa[(i + 2) % 3] = *(const half8*)(ap + dkj * 8192 + kbj * 16);
            }
            if (i < 19) {
                const int j = i + 1, dkj = j >> 2, kbj = j & 3;
                #pragma unroll
                for (int s = 0; s < 4; ++s)
                    Bb[j & 1][s] = *(const half8*)(bps[s] + dkj * P1T_STRIDE + kbj * 16);
            }
            #pragma unroll
            for (int s = 0; s < 4; ++s)
                acc[s] = __builtin_amdgcn_mfma_f32_32x32x16_f16(Aa[i % 3], Bb[i & 1][s], acc[s], 0, 0, 0);
        }
        #pragma unroll
        for (int s = 0; s < 4; ++s) {
            const int P = 1 + (ntb + s) * 16 + (col >> 1);
            pool_store(acc[s], p2T + P * P2T_STRIDE + mt * 32 + 4 * g);
        }
    }
    // ---- cross-barrier prefetch: conv3 A[0..1]
    const _Float16* ap3 = w3p + (wave * 32 + col) * 128 + g * 8;  // + dk*32768 + kb*16
    half8 a3_0 = *(const half8*)(ap3);
    half8 a3_1 = *(const half8*)(ap3 + 16);
    __syncthreads();

    // ==== conv3: wave -> (mt = wave, 4 nts); 24 steps (dk=i>>3, kb=i&7) streamed; in-reg mean ====
    {
        const int mt = wave;
        const _Float16* ap = ap3;
        const _Float16* bps[4];
        #pragma unroll
        for (int s = 0; s < 4; ++s)
            bps[s] = p2T + (s * 32 + col) * P2T_STRIDE + g * 8;    // + dk*136 + kb*16
        floatx16 acc[4];
        #pragma unroll
        for (int q4 = 0; q4 < 4; ++q4) {
            float4 bq = *(const float4*)&lds[B3_OFF + mt * 32 + 8 * q4 + 4 * g];
            #pragma unroll
            for (int s = 0; s < 4; ++s) {
                acc[s][4 * q4 + 0] = bq.x; acc[s][4 * q4 + 1] = bq.y;
                acc[s][4 * q4 + 2] = bq.z; acc[s][4 * q4 + 3] = bq.w;
            }
        }
        half8 Aa[3], Bb[2][4];
        Aa[0] = a3_0;
        Aa[1] = a3_1;
        #pragma unroll
        for (int s = 0; s < 4; ++s) Bb[0][s] = *(const half8*)(bps[s]);
        #pragma unroll
        for (int i = 0; i < 24; ++i) {
            if (i < 22) {
                const int j = i + 2, dkj = j >> 3, kbj = j & 7;
                Aa[(i + 2) % 3] = *(const half8*)(ap + dkj * 32768 + kbj * 16);
            }
            if (i < 23) {
                const int j = i + 1, dkj = j >> 3, kbj = j & 7;
                #pragma unroll
                for (int s = 0; s < 4; ++s)
                    Bb[j & 1][s] = *(const half8*)(bps[s] + dkj * P2T_STRIDE + kbj * 16);
            }
            #pragma unroll
            for (int s = 0; s < 4; ++s)
                acc[s] = __builtin_amdgcn_mfma_f32_32x32x16_f16(Aa[i % 3], Bb[i & 1][s], acc[s], 0, 0, 0);
        }
        // relu + pool(xor1, duplicated) + col-sum over all 128 positions (dup -> /128)
        #pragma unroll
        for (int r = 0; r < 16; ++r) {
            float srow = 0.f;
            #pragma unroll
            for (int s = 0; s < 4; ++s) {
                float v = fmaxf(acc[s][r], 0.f);
                srow += fmaxf(v, __shfl_xor(v, 1));
            }
            float s16 = dpp_rowsum16(srow);
            float s32 = s16 + __shfl_xor(s16, 16);
            if ((lane & 31) == 15) {
                int ch = mt * 32 + (r & 3) + 8 * (r >> 2) + 4 * g;
                lds[SCR_OFF + ch] = s32 * (1.f / 128.f);
            }
        }
    }
    // ---- cross-barrier prefetch: fc weight group 0 (acc dead; 16 VGPR through barrier)
    float4 Wc[4];
    {
        const int o0p = wave * 16;
        #pragma unroll
        for (int k = 0; k < 4; ++k)
            Wc[k] = *(const float4*)&fcw[(o0p + k) * 256 + 4 * lane];
    }
    __syncthreads();

    // ---- fc (256->128) + relu + FUSED batchnorm/zh-store/sq-partials; pipelined weights
    {
        const float4 xv = *(const float4*)&lds[SCR_OFF + 4 * lane];
        float sqpart = 0.f;
        #pragma unroll
        for (int j = 0; j < 4; ++j) {
            const int o0 = wave * 16 + j * 4;
            float4 Wn[4];
            if (j < 3) {
                #pragma unroll
                for (int k = 0; k < 4; ++k)
                    Wn[k] = *(const float4*)&fcw[(o0 + 4 + k) * 256 + 4 * lane];
            }
            float s0 = Wc[0].x * xv.x + Wc[0].y * xv.y + Wc[0].z * xv.z + Wc[0].w * xv.w;
            float s1 = Wc[1].x * xv.x + Wc[1].y * xv.y + Wc[1].z * xv.z + Wc[1].w * xv.w;
            float s2 = Wc[2].x * xv.x + Wc[2].y * xv.y + Wc[2].z * xv.z + Wc[2].w * xv.w;
            float s3 = Wc[3].x * xv.x + Wc[3].y * xv.y + Wc[3].z * xv.z + Wc[3].w * xv.w;
            #pragma unroll
            for (int off = 32; off > 0; off >>= 1) {
                s0 += __shfl_down(s0, off);
                s1 += __shfl_down(s1, off);
                s2 += __shfl_down(s2, off);
                s3 += __shfl_down(s3, off);
            }
            if (lane == 0) {
                float sv[4] = {s0, s1, s2, s3};
                half2v zp0, zp1;
                #pragma unroll
                for (int k = 0; k < 4; ++k) {
                    float hv = fmaxf(sv[k] + lds[PR_OFF + o0 + k], 0.f);
                    float zv = lds[PR_OFF + 128 + o0 + k] * (hv - lds[PR_OFF + 384 + o0 + k])
                             * (1.f / sqrtf(lds[PR_OFF + 512 + o0 + k] + 1e-5f))
                             + lds[PR_OFF + 256 + o0 + k];
                    _Float16 zq = (_Float16)zv;
                    if (k < 2) zp0[k] = zq; else zp1[k - 2] = zq;
                    float zqf = (float)zq;
                    sqpart += zqf * zqf;
                }
                *(half2v*)(zh + (size_t)n * 128 + o0)     = zp0;
                *(half2v*)(zh + (size_t)n * 128 + o0 + 2) = zp1;
            }
            if (j < 3) {
                #pragma unroll
                for (int k = 0; k < 4; ++k) Wc[k] = Wn[k];
            }
        }
        if (lane == 0) lds[SCR_OFF + 256 + wave] = sqpart;
    }
    __syncthreads();
    if (t == 0) {
        float s = 0.f;
        #pragma unroll
        for (int w = 0; w < 8; ++w) s += lds[SCR_OFF + 256 + w];
        sqout[n] = s;
    }
}

// ---- pairwise via f16 MFMA: 128x128 tile/block, 4 waves, each 64x64 quadrant
// (round-3 measured-best structure, PLAIN stores. Measured-rejected variants:
// setprio [m190+r5, -12us], symmetry/mirror [r8, -15us], 512-thr [r10, neutral],
// non-temporal stores [r11, -17us: L2 write-combining was helping].)
#define PW_STRIDE 136   // f16; 68 words == 4 mod 32 -> conflict-free b128
#define PW_LDS_BYTES (2 * 128 * PW_STRIDE * 2)

__global__ __launch_bounds__(256, 2)
void pairwise_mfma(const _Float16* __restrict__ zh, const float* __restrict__ sq,
                   const int* __restrict__ u, float* __restrict__ out)
{
    extern __shared__ float ldsf[];
    _Float16* at = (_Float16*)ldsf;                  // [128][136]
    _Float16* bt = at + 128 * PW_STRIDE;
    const int t = threadIdx.x;
    const int i0 = blockIdx.y * 128;
    const int j0 = blockIdx.x * 128;

    #pragma unroll
    for (int r4 = 0; r4 < 8; ++r4) {
        int idx = t + 256 * r4;            // 0..2047
        int row = idx >> 4, c8 = (idx & 15) * 8;
        *(half8*)(at + row * PW_STRIDE + c8) = *(const half8*)(zh + (size_t)(i0 + row) * 128 + c8);
        *(half8*)(bt + row * PW_STRIDE + c8) = *(const half8*)(zh + (size_t)(j0 + row) * 128 + c8);
    }
    __syncthreads();

    const int lane = t & 63, wave = t >> 6;
    const int g = lane >> 5, col = lane & 31;
    const int ib = (wave & 1) * 64, jb = (wave >> 1) * 64;

    half8 A[2][8];
    #pragma unroll
    for (int mt = 0; mt < 2; ++mt)
        #pragma unroll
        for (int kb = 0; kb < 8; ++kb)
            A[mt][kb] = *(const half8*)(at + (ib + mt * 32 + col) * PW_STRIDE + kb * 16 + g * 8);

    floatx16 acc[2][2];
    #pragma unroll
    for (int a = 0; a < 2; ++a)
        #pragma unroll
        for (int b = 0; b < 2; ++b)
            #pragma unroll
            for (int r = 0; r < 16; ++r) acc[a][b][r] = 0.f;

    #pragma unroll
    for (int nt = 0; nt < 2; ++nt)
        #pragma unroll
        for (int kb = 0; kb < 8; ++kb) {
            half8 B = *(const half8*)(bt + (jb + nt * 32 + col) * PW_STRIDE + kb * 16 + g * 8);
            acc[0][nt] = __builtin_amdgcn_mfma_f32_32x32x16_f16(A[0][kb], B, acc[0][nt], 0, 0, 0);
            acc[1][nt] = __builtin_amdgcn_mfma_f32_32x32x16_f16(A[1][kb], B, acc[1][nt], 0, 0, 0);
        }

    #pragma unroll
    for (int nt = 0; nt < 2; ++nt) {
        const int j = j0 + jb + nt * 32 + col;
        const float sqj = sq[j];
        const int uj = u[j];
        #pragma unroll
        for (int mt = 0; mt < 2; ++mt) {
            #pragma unroll
            for (int r = 0; r < 16; ++r) {
                const int i = i0 + ib + mt * 32 + (r & 3) + 8 * (r >> 2) + 4 * g;
                float res;
                if (i == j) {
                    res = 0.f;
                } else {
                    float d2 = sq[i] + sqj - 2.f * acc[mt][nt][r];
                    float d = sqrtf(fmaxf(d2, 0.f));
                    int ui = u[i];
                    res = (ui == uj && ui >= 0) ? d : fmaxf(1.f - d, 0.f);
                }
                out[(size_t)i * 4096 + j] = res;
            }
        }
    }
}

extern "C" void kernel_launch(void* const* d_in, const int* in_sizes, int n_in,
                              void* d_out, int out_size, void* d_ws, size_t ws_size,
                              hipStream_t stream)
{
    const float* samples = (const float*)d_in[0];
    const int*   info    = (const int*)d_in[1];
    const float* w1  = (const float*)d_in[2];
    const float* b1  = (const float*)d_in[3];
    const float* w2  = (const float*)d_in[4];
    const float* b2  = (const float*)d_in[5];
    const float* w3  = (const float*)d_in[6];
    const float* b3  = (const float*)d_in[7];
    const float* fcw = (const float*)d_in[8];
    const float* fcb = (const float*)d_in[9];
    const float* g   = (const float*)d_in[10];
    const float* be  = (const float*)d_in[11];
    const float* bm  = (const float*)d_in[12];
    const float* bv  = (const float*)d_in[13];
    float* out = (float*)d_out;

    // ws: zh f16 [4096*128] @0 (1 MB); sq f32 @1MB (16 KB); u int @1MB+16K (16 KB);
    //     w1p/w2p/w3p f16 @1MB+32K
    _Float16* zhws = (_Float16*)d_ws;
    float*    sqws = (float*)((char*)d_ws + (1 << 20));
    int*      uws  = (int*)((char*)d_ws + (1 << 20) + 16384);
    _Float16* wp   = (_Float16*)((char*)d_ws + (1 << 20) + 32768);
    _Float16* w1p = wp;               // 8192
    _Float16* w2p = wp + 8192;        // 40960
    _Float16* w3p = wp + 49152;       // 98304

    hipLaunchKernelGGL(prep_weights, dim3(576), dim3(256), 0, stream,
                       w1, w2, w3, w1p, w2p, w3p);

    hipLaunchKernelGGL(cnn_fused, dim3(NS), dim3(512),
                       LDS_MAIN_FLOATS * sizeof(float), stream,
                       samples, info, w1p, w2p, w3p, b1, b2, b3, fcw, fcb,
                       g, be, bm, bv, zhws, sqws, uws);

    hipLaunchKernelGGL(pairwise_mfma, dim3(32, 32), dim3(256),
                       PW_LDS_BYTES, stream,
                       zhws, sqws, uws, out);
}

// Round 15
// 400.705 us; speedup vs baseline: 1.0654x; 1.0654x over previous
//
#include <hip/hip_runtime.h>
#include <math.h>

#define NS 4096

typedef _Float16 half8 __attribute__((ext_vector_type(8)));
typedef _Float16 half2v __attribute__((ext_vector_type(2)));
typedef __fp16 fp16x2 __attribute__((ext_vector_type(2)));
typedef float floatx16 __attribute__((ext_vector_type(16)));

// ---------------- LDS layout (f32 word offsets), main kernel ----------------
#define P1T_OFF     0
#define P1T_STRIDE  72
#define P2T_OFF     9360
#define P2T_STRIDE  136
#define XC_OFF      9360
#define XC_STRIDE   648
#define SCR_OFF     1024
#define B1_OFF      18200
#define B2_OFF      18264
#define B3_OFF      18392
#define PR_OFF      18648
#define LDS_MAIN_FLOATS 19288   // 77,152 B -> 2 blocks/CU

// ---------------- weight prep: f32 -> f16 MFMA layouts ----------------
// w1p[64 m][128 k] (k<100 real, else 0); w2p[5][128 m][64 i]; w3p[3][256 m][128 i]
__global__ void prep_weights(const float* __restrict__ w1,
                             const float* __restrict__ w2,
                             const float* __restrict__ w3,
                             _Float16* __restrict__ w1p,
                             _Float16* __restrict__ w2p,
                             _Float16* __restrict__ w3p)
{
    int gid = blockIdx.x * 256 + threadIdx.x;
    if (gid < 8192) {
        int m = gid >> 7, k = gid & 127;
        w1p[gid] = (k < 100) ? (_Float16)w1[m * 100 + k] : (_Float16)0.f;
    } else if (gid < 49152) {
        int r = gid - 8192;
        int dk = r >> 13, rem = r & 8191;
        int m = rem >> 6, i = rem & 63;
        w2p[r] = (_Float16)w2[(m * 64 + i) * 5 + dk];
    } else if (gid < 147456) {
        int r = gid - 49152;
        int dk = r >> 15, rem = r & 32767;
        int m = rem >> 7, i = rem & 127;
        w3p[r] = (_Float16)w3[(m * 128 + i) * 3 + dk];
    }
}

// inclusive add-scan within each 16-lane row via DPP row_shr; lane (l%16)==15 holds row sum
__device__ __forceinline__ float dpp_rowsum16(float v) {
    int x;
    x = __builtin_amdgcn_update_dpp(0, __float_as_int(v), 0x111, 0xF, 0xF, true);
    v += __int_as_float(x);
    x = __builtin_amdgcn_update_dpp(0, __float_as_int(v), 0x112, 0xF, 0xF, true);
    v += __int_as_float(x);
    x = __builtin_amdgcn_update_dpp(0, __float_as_int(v), 0x114, 0xF, 0xF, true);
    v += __int_as_float(x);
    x = __builtin_amdgcn_update_dpp(0, __float_as_int(v), 0x118, 0xF, 0xF, true);
    v += __int_as_float(x);
    return v;
}

// C/D 32x32 layout: col = lane&31, row = (reg&3) + 8*(reg>>2) + 4*(lane>>5)
// A/B layout: m|n = lane&31, k = (lane>>5)*8 + j (+16*kb)

__global__ __launch_bounds__(512, 4)
void cnn_fused(const float* __restrict__ samples, const int* __restrict__ info,
               const _Float16* __restrict__ w1p,
               const _Float16* __restrict__ w2p,
               const _Float16* __restrict__ w3p,
               const float* __restrict__ b1, const float* __restrict__ b2,
               const float* __restrict__ b3,
               const float* __restrict__ fcw, const float* __restrict__ fcb,
               const float* __restrict__ gamma_, const float* __restrict__ beta_,
               const float* __restrict__ bnm, const float* __restrict__ bnv,
               _Float16* __restrict__ zh, float* __restrict__ sqout,
               int* __restrict__ uout)
{
    extern __shared__ float lds[];
    _Float16* p1T = (_Float16*)(lds + P1T_OFF);
    _Float16* p2T = (_Float16*)(lds + P2T_OFF);
    _Float16* xc  = (_Float16*)(lds + XC_OFF);     // aliases p2T (dead after conv1)

    const int n    = blockIdx.x;
    const int t    = threadIdx.x;
    const int lane = t & 63;
    const int wave = t >> 6;
    const int g    = lane >> 5;
    const int col  = lane & 31;

    // ---- stage: xc[c][u] = x[u + c - 49] as f16; wave w fills copy c=w (no div)
    {
        const float* sp = samples + n * 512;
        const int c = wave;
        for (int u = lane; u < XC_STRIDE; u += 64) {
            int src = u + c - 49;
            xc[c * XC_STRIDE + u] = (_Float16)((src >= 0 && src < 512) ? sp[src] : 0.f);
        }
    }
    // ---- biases + fc/bn params to LDS (hidden under conv1)
    if (t < 64)              lds[B1_OFF + t] = b1[t];
    if (t >= 64 && t < 192)  lds[B2_OFF + (t - 64)] = b2[t - 64];
    if (t >= 192 && t < 448) lds[B3_OFF + (t - 192)] = b3[t - 192];
    for (int i = t; i < 640; i += 512) {
        int k = i & 127;
        const float* p = (i < 128) ? fcb : (i < 256) ? gamma_ : (i < 384) ? beta_
                       : (i < 512) ? bnm : bnv;
        lds[PR_OFF + i] = p[k];
    }
    // ---- zero p1T halos: rows {0,1,258,259} (36 f32 each)
    if (t < 144) {
        int rr = t / 36, c4 = t - rr * 36;
        int row = (rr < 2) ? rr : (256 + rr);
        lds[P1T_OFF + row * 36 + c4] = 0.f;
    }
    if (t == 0) uout[n] = (info[2 * n + 1] == 1) ? info[2 * n] : -1;

    // ---- cross-barrier prefetch: conv1 A[0..1] (global, independent of LDS)
    const int mt1 = wave >> 2;
    const _Float16* ap1 = w1p + (mt1 * 32 + col) * 128 + g * 8;
    half8 a1_0 = *(const half8*)(ap1);
    half8 a1_1 = *(const half8*)(ap1 + 16);
    __syncthreads();

    // pooled relu store, packed-f16 path: cvt_pkrtz first (monotone; max/relu commute
    // with cvt exactly), then packed relu + lane-pair pool via packed max.
    // ~32 VALU ops/acc vs ~56 scalar (pool_store was ~30% of kernel VALU).
    // absmax tripwire: RTZ-vs-RNE may shift absmax slightly; revert if test fails.
    auto pool_store = [&](floatx16& acc, _Float16* dst) {
        half2v pk[8];
        const half2v zz = {(_Float16)0.f, (_Float16)0.f};
        #pragma unroll
        for (int q = 0; q < 8; ++q) {
            fp16x2 cr = __builtin_amdgcn_cvt_pkrtz(acc[2 * q], acc[2 * q + 1]);
            half2v c = __builtin_bit_cast(half2v, cr);
            c = __builtin_elementwise_max(c, zz);               // relu (packed)
            int ci = __builtin_bit_cast(int, c);
            int pi = __shfl_xor(ci, 1);
            half2v p = __builtin_bit_cast(half2v, pi);
            pk[q] = __builtin_elementwise_max(c, p);            // pool (packed)
        }
        if (!(lane & 1)) {
            #pragma unroll
            for (int rq = 0; rq < 4; ++rq) {
                *(half2v*)(dst + 8 * rq)     = pk[2 * rq];
                *(half2v*)(dst + 8 * rq + 2) = pk[2 * rq + 1];
            }
        }
    };

    // ======== conv1: wave -> (mt = wave>>2, 4 nts); K=112; kb-outer 4-chain stream ========
    {
        const int mt   = mt1;
        const int ntb1 = (wave & 3) * 4;
        const _Float16* ap = ap1;
        const _Float16* bps[4];
        #pragma unroll
        for (int s = 0; s < 4; ++s) {
            const int nt = ntb1 + s;
            const int nn = nt * 32 + col;
            const int c  = nn & 7;
            bps[s] = xc + c * XC_STRIDE + (nn - c) + g * 8;
        }
        floatx16 acc[4];
        #pragma unroll
        for (int q4 = 0; q4 < 4; ++q4) {
            float4 bq = *(const float4*)&lds[B1_OFF + mt * 32 + 8 * q4 + 4 * g];
            #pragma unroll
            for (int s = 0; s < 4; ++s) {
                acc[s][4 * q4 + 0] = bq.x; acc[s][4 * q4 + 1] = bq.y;
                acc[s][4 * q4 + 2] = bq.z; acc[s][4 * q4 + 3] = bq.w;
            }
        }
        half8 Aa[3], Bb[2][4];
        Aa[0] = a1_0;
        Aa[1] = a1_1;
        #pragma unroll
        for (int s = 0; s < 4; ++s) Bb[0][s] = *(const half8*)(bps[s]);
        #pragma unroll
        for (int i = 0; i < 7; ++i) {
            if (i < 5)
                Aa[(i + 2) % 3] = *(const half8*)(ap + (i + 2) * 16);
            if (i < 6) {
                #pragma unroll
                for (int s = 0; s < 4; ++s)
                    Bb[(i + 1) & 1][s] = *(const half8*)(bps[s] + (i + 1) * 16);
            }
            #pragma unroll
            for (int s = 0; s < 4; ++s)
                acc[s] = __builtin_amdgcn_mfma_f32_32x32x16_f16(Aa[i % 3], Bb[i & 1][s], acc[s], 0, 0, 0);
        }
        #pragma unroll
        for (int s = 0; s < 4; ++s) {
            const int P = 2 + (ntb1 + s) * 16 + (col >> 1);
            pool_store(acc[s], p1T + P * P1T_STRIDE + mt * 32 + 4 * g);
        }
    }
    // ---- cross-barrier prefetch: conv2 A[0..1] (acc dead here; lives only through barrier)
    const int mt2 = wave & 3;
    const _Float16* ap2 = w2p + (mt2 * 32 + col) * 64 + g * 8;   // + dk*8192 + kb*16
    half8 a2_0 = *(const half8*)(ap2);
    half8 a2_1 = *(const half8*)(ap2 + 16);
    __syncthreads();

    // ======== conv2: wave -> (mt = wave&3, 4 nts); 20 steps (dk=i>>2, kb=i&3) streamed ========
    {
        // zero p2T halo rows {0,129} now that xc (aliased) is dead
        if (t < 136) {
            int row = (t < 68) ? 0 : 129;
            int c4 = (t < 68) ? t : (t - 68);
            lds[P2T_OFF + row * 68 + c4] = 0.f;
        }
        const int mt  = mt2;
        const int ntb = (wave >> 2) * 4;
        const _Float16* ap = ap2;
        const _Float16* bps[4];
        #pragma unroll
        for (int s = 0; s < 4; ++s)
            bps[s] = p1T + ((ntb + s) * 32 + col) * P1T_STRIDE + g * 8;  // + dk*72 + kb*16
        floatx16 acc[4];
        #pragma unroll
        for (int q4 = 0; q4 < 4; ++q4) {
            float4 bq = *(const float4*)&lds[B2_OFF + mt * 32 + 8 * q4 + 4 * g];
            #pragma unroll
            for (int s = 0; s < 4; ++s) {
                acc[s][4 * q4 + 0] = bq.x; acc[s][4 * q4 + 1] = bq.y;
                acc[s][4 * q4 + 2] = bq.z; acc[s][4 * q4 + 3] = bq.w;
            }
        }
        half8 Aa[3], Bb[2][4];
        Aa[0] = a2_0;
        Aa[1] = a2_1;
        #pragma unroll
        for (int s = 0; s < 4; ++s) Bb[0][s] = *(const half8*)(bps[s]);
        #pragma unroll
        for (int i = 0; i < 20; ++i) {
            if (i < 18) {
                const int j = i + 2, dkj = j >> 2, kbj = j & 3;
                Aa[(i + 2) % 3] = *(const half8*)(ap + dkj * 8192 + kbj * 16);
            }
            if (i < 19) {
                const int j = i + 1, dkj = j >> 2, kbj = j & 3;
                #pragma unroll
                for (int s = 0; s < 4; ++s)
                    Bb[j & 1][s] = *(const half8*)(bps[s] + dkj * P1T_STRIDE + kbj * 16);
            }
            #pragma unroll
            for (int s = 0; s < 4; ++s)
                acc[s] = __builtin_amdgcn_mfma_f32_32x32x16_f16(Aa[i % 3], Bb[i & 1][s], acc[s], 0, 0, 0);
        }
        #pragma unroll
        for (int s = 0; s < 4; ++s) {
            const int P = 1 + (ntb + s) * 16 + (col >> 1);
            pool_store(acc[s], p2T + P * P2T_STRIDE + mt * 32 + 4 * g);
        }
    }
    // ---- cross-barrier prefetch: conv3 A[0..1]
    const _Float16* ap3 = w3p + (wave * 32 + col) * 128 + g * 8;  // + dk*32768 + kb*16
    half8 a3_0 = *(const half8*)(ap3);
    half8 a3_1 = *(const half8*)(ap3 + 16);
    __syncthreads();

    // ==== conv3: wave -> (mt = wave, 4 nts); 24 steps (dk=i>>3, kb=i&7) streamed; in-reg mean ====
    // (epilogue kept in f32: mean-sum precision feeds z -> pairwise)
    {
        const int mt = wave;
        const _Float16* ap = ap3;
        const _Float16* bps[4];
        #pragma unroll
        for (int s = 0; s < 4; ++s)
            bps[s] = p2T + (s * 32 + col) * P2T_STRIDE + g * 8;    // + dk*136 + kb*16
        floatx16 acc[4];
        #pragma unroll
        for (int q4 = 0; q4 < 4; ++q4) {
            float4 bq = *(const float4*)&lds[B3_OFF + mt * 32 + 8 * q4 + 4 * g];
            #pragma unroll
            for (int s = 0; s < 4; ++s) {
                acc[s][4 * q4 + 0] = bq.x; acc[s][4 * q4 + 1] = bq.y;
                acc[s][4 * q4 + 2] = bq.z; acc[s][4 * q4 + 3] = bq.w;
            }
        }
        half8 Aa[3], Bb[2][4];
        Aa[0] = a3_0;
        Aa[1] = a3_1;
        #pragma unroll
        for (int s = 0; s < 4; ++s) Bb[0][s] = *(const half8*)(bps[s]);
        #pragma unroll
        for (int i = 0; i < 24; ++i) {
            if (i < 22) {
                const int j = i + 2, dkj = j >> 3, kbj = j & 7;
                Aa[(i + 2) % 3] = *(const half8*)(ap + dkj * 32768 + kbj * 16);
            }
            if (i < 23) {
                const int j = i + 1, dkj = j >> 3, kbj = j & 7;
                #pragma unroll
                for (int s = 0; s < 4; ++s)
                    Bb[j & 1][s] = *(const half8*)(bps[s] + dkj * P2T_STRIDE + kbj * 16);
            }
            #pragma unroll
            for (int s = 0; s < 4; ++s)
                acc[s] = __builtin_amdgcn_mfma_f32_32x32x16_f16(Aa[i % 3], Bb[i & 1][s], acc[s], 0, 0, 0);
        }
        // relu + pool(xor1, duplicated) + col-sum over all 128 positions (dup -> /128)
        #pragma unroll
        for (int r = 0; r < 16; ++r) {
            float srow = 0.f;
            #pragma unroll
            for (int s = 0; s < 4; ++s) {
                float v = fmaxf(acc[s][r], 0.f);
                srow += fmaxf(v, __shfl_xor(v, 1));
            }
            float s16 = dpp_rowsum16(srow);
            float s32 = s16 + __shfl_xor(s16, 16);
            if ((lane & 31) == 15) {
                int ch = mt * 32 + (r & 3) + 8 * (r >> 2) + 4 * g;
                lds[SCR_OFF + ch] = s32 * (1.f / 128.f);
            }
        }
    }
    // ---- cross-barrier prefetch: fc weight group 0 (acc dead; 16 VGPR through barrier)
    float4 Wc[4];
    {
        const int o0p = wave * 16;
        #pragma unroll
        for (int k = 0; k < 4; ++k)
            Wc[k] = *(const float4*)&fcw[(o0p + k) * 256 + 4 * lane];
    }
    __syncthreads();

    // ---- fc (256->128) + relu + FUSED batchnorm/zh-store/sq-partials; pipelined weights
    {
        const float4 xv = *(const float4*)&lds[SCR_OFF + 4 * lane];
        float sqpart = 0.f;
        #pragma unroll
        for (int j = 0; j < 4; ++j) {
            const int o0 = wave * 16 + j * 4;
            float4 Wn[4];
            if (j < 3) {
                #pragma unroll
                for (int k = 0; k < 4; ++k)
                    Wn[k] = *(const float4*)&fcw[(o0 + 4 + k) * 256 + 4 * lane];
            }
            float s0 = Wc[0].x * xv.x + Wc[0].y * xv.y + Wc[0].z * xv.z + Wc[0].w * xv.w;
            float s1 = Wc[1].x * xv.x + Wc[1].y * xv.y + Wc[1].z * xv.z + Wc[1].w * xv.w;
            float s2 = Wc[2].x * xv.x + Wc[2].y * xv.y + Wc[2].z * xv.z + Wc[2].w * xv.w;
            float s3 = Wc[3].x * xv.x + Wc[3].y * xv.y + Wc[3].z * xv.z + Wc[3].w * xv.w;
            #pragma unroll
            for (int off = 32; off > 0; off >>= 1) {
                s0 += __shfl_down(s0, off);
                s1 += __shfl_down(s1, off);
                s2 += __shfl_down(s2, off);
                s3 += __shfl_down(s3, off);
            }
            if (lane == 0) {
                float sv[4] = {s0, s1, s2, s3};
                half2v zp0, zp1;
                #pragma unroll
                for (int k = 0; k < 4; ++k) {
                    float hv = fmaxf(sv[k] + lds[PR_OFF + o0 + k], 0.f);
                    float zv = lds[PR_OFF + 128 + o0 + k] * (hv - lds[PR_OFF + 384 + o0 + k])
                             * (1.f / sqrtf(lds[PR_OFF + 512 + o0 + k] + 1e-5f))
                             + lds[PR_OFF + 256 + o0 + k];
                    _Float16 zq = (_Float16)zv;
                    if (k < 2) zp0[k] = zq; else zp1[k - 2] = zq;
                    float zqf = (float)zq;
                    sqpart += zqf * zqf;
                }
                *(half2v*)(zh + (size_t)n * 128 + o0)     = zp0;
                *(half2v*)(zh + (size_t)n * 128 + o0 + 2) = zp1;
            }
            if (j < 3) {
                #pragma unroll
                for (int k = 0; k < 4; ++k) Wc[k] = Wn[k];
            }
        }
        if (lane == 0) lds[SCR_OFF + 256 + wave] = sqpart;
    }
    __syncthreads();
    if (t == 0) {
        float s = 0.f;
        #pragma unroll
        for (int w = 0; w < 8; ++w) s += lds[SCR_OFF + 256 + w];
        sqout[n] = s;
    }
}

// ---- pairwise via f16 MFMA: 128x128 tile/block, 4 waves, each 64x64 quadrant
// (round-3 measured-best structure, PLAIN stores. Measured-rejected variants:
// setprio [m190+r5, -12us], symmetry/mirror [r8, -15us], 512-thr [r10, neutral],
// non-temporal stores [r11, -17us: L2 write-combining was helping].)
#define PW_STRIDE 136   // f16; 68 words == 4 mod 32 -> conflict-free b128
#define PW_LDS_BYTES (2 * 128 * PW_STRIDE * 2)

__global__ __launch_bounds__(256, 2)
void pairwise_mfma(const _Float16* __restrict__ zh, const float* __restrict__ sq,
                   const int* __restrict__ u, float* __restrict__ out)
{
    extern __shared__ float ldsf[];
    _Float16* at = (_Float16*)ldsf;                  // [128][136]
    _Float16* bt = at + 128 * PW_STRIDE;
    const int t = threadIdx.x;
    const int i0 = blockIdx.y * 128;
    const int j0 = blockIdx.x * 128;

    #pragma unroll
    for (int r4 = 0; r4 < 8; ++r4) {
        int idx = t + 256 * r4;            // 0..2047
        int row = idx >> 4, c8 = (idx & 15) * 8;
        *(half8*)(at + row * PW_STRIDE + c8) = *(const half8*)(zh + (size_t)(i0 + row) * 128 + c8);
        *(half8*)(bt + row * PW_STRIDE + c8) = *(const half8*)(zh + (size_t)(j0 + row) * 128 + c8);
    }
    __syncthreads();

    const int lane = t & 63, wave = t >> 6;
    const int g = lane >> 5, col = lane & 31;
    const int ib = (wave & 1) * 64, jb = (wave >> 1) * 64;

    half8 A[2][8];
    #pragma unroll
    for (int mt = 0; mt < 2; ++mt)
        #pragma unroll
        for (int kb = 0; kb < 8; ++kb)
            A[mt][kb] = *(const half8*)(at + (ib + mt * 32 + col) * PW_STRIDE + kb * 16 + g * 8);

    floatx16 acc[2][2];
    #pragma unroll
    for (int a = 0; a < 2; ++a)
        #pragma unroll
        for (int b = 0; b < 2; ++b)
            #pragma unroll
            for (int r = 0; r < 16; ++r) acc[a][b][r] = 0.f;

    #pragma unroll
    for (int nt = 0; nt < 2; ++nt)
        #pragma unroll
        for (int kb = 0; kb < 8; ++kb) {
            half8 B = *(const half8*)(bt + (jb + nt * 32 + col) * PW_STRIDE + kb * 16 + g * 8);
            acc[0][nt] = __builtin_amdgcn_mfma_f32_32x32x16_f16(A[0][kb], B, acc[0][nt], 0, 0, 0);
            acc[1][nt] = __builtin_amdgcn_mfma_f32_32x32x16_f16(A[1][kb], B, acc[1][nt], 0, 0, 0);
        }

    #pragma unroll
    for (int nt = 0; nt < 2; ++nt) {
        const int j = j0 + jb + nt * 32 + col;
        const float sqj = sq[j];
        const int uj = u[j];
        #pragma unroll
        for (int mt = 0; mt < 2; ++mt) {
            #pragma unroll
            for (int r = 0; r < 16; ++r) {
                const int i = i0 + ib + mt * 32 + (r & 3) + 8 * (r >> 2) + 4 * g;
                float res;
                if (i == j) {
                    res = 0.f;
                } else {
                    float d2 = sq[i] + sqj - 2.f * acc[mt][nt][r];
                    float d = sqrtf(fmaxf(d2, 0.f));
                    int ui = u[i];
                    res = (ui == uj && ui >= 0) ? d : fmaxf(1.f - d, 0.f);
                }
                out[(size_t)i * 4096 + j] = res;
            }
        }
    }
}

extern "C" void kernel_launch(void* const* d_in, const int* in_sizes, int n_in,
                              void* d_out, int out_size, void* d_ws, size_t ws_size,
                              hipStream_t stream)
{
    const float* samples = (const float*)d_in[0];
    const int*   info    = (const int*)d_in[1];
    const float* w1  = (const float*)d_in[2];
    const float* b1  = (const float*)d_in[3];
    const float* w2  = (const float*)d_in[4];
    const float* b2  = (const float*)d_in[5];
    const float* w3  = (const float*)d_in[6];
    const float* b3  = (const float*)d_in[7];
    const float* fcw = (const float*)d_in[8];
    const float* fcb = (const float*)d_in[9];
    const float* g   = (const float*)d_in[10];
    const float* be  = (const float*)d_in[11];
    const float* bm  = (const float*)d_in[12];
    const float* bv  = (const float*)d_in[13];
    float* out = (float*)d_out;

    // ws: zh f16 [4096*128] @0 (1 MB); sq f32 @1MB (16 KB); u int @1MB+16K (16 KB);
    //     w1p/w2p/w3p f16 @1MB+32K
    _Float16* zhws = (_Float16*)d_ws;
    float*    sqws = (float*)((char*)d_ws + (1 << 20));
    int*      uws  = (int*)((char*)d_ws + (1 << 20) + 16384);
    _Float16* wp   = (_Float16*)((char*)d_ws + (1 << 20) + 32768);
    _Float16* w1p = wp;               // 8192
    _Float16* w2p = wp + 8192;        // 40960
    _Float16* w3p = wp + 49152;       // 98304

    hipLaunchKernelGGL(prep_weights, dim3(576), dim3(256), 0, stream,
                       w1, w2, w3, w1p, w2p, w3p);

    hipLaunchKernelGGL(cnn_fused, dim3(NS), dim3(512),
                       LDS_MAIN_FLOATS * sizeof(float), stream,
                       samples, info, w1p, w2p, w3p, b1, b2, b3, fcw, fcb,
                       g, be, bm, bv, zhws, sqws, uws);

    hipLaunchKernelGGL(pairwise_mfma, dim3(32, 32), dim3(256),
                       PW_LDS_BYTES, stream,
                       zhws, sqws, uws, out);
}